// Round 2
// baseline (1591.379 us; speedup 1.0000x reference)
//
#include <hip/hip_runtime.h>
#include <cstdint>
#include <cstddef>

#define T_TOKENS 16384
#define DMODEL 1024
#define HID 4096
#define NEXP 8
#define NPAIRS 32768   // T_TOKENS * 2

typedef _Float16 half8 __attribute__((ext_vector_type(8)));
typedef _Float16 half4 __attribute__((ext_vector_type(4)));
typedef float f32x4 __attribute__((ext_vector_type(4)));

__device__ __forceinline__ void gload_lds16(const void* g, void* l) {
  __builtin_amdgcn_global_load_lds(
      (const __attribute__((address_space(1))) unsigned int*)g,
      (__attribute__((address_space(3))) unsigned int*)l, 16, 0, 0);
}

// ---------------- gate: scores, top-2, softmax, per-expert counts ------------
__global__ __launch_bounds__(256) void k_gate(const float* __restrict__ x,
                                              const float* __restrict__ gw,
                                              int2* __restrict__ route_e,
                                              float2* __restrict__ route_w,
                                              int* __restrict__ counts) {
  __shared__ int lcnt[NEXP];
  int tid = threadIdx.x, lane = tid & 63, w = tid >> 6;
  if (tid < NEXP) lcnt[tid] = 0;
  __syncthreads();
  int t = blockIdx.x * 4 + w;
  const float4* xr = (const float4*)(x + (size_t)t * DMODEL);
  double s[NEXP];
#pragma unroll
  for (int e = 0; e < NEXP; e++) s[e] = 0.0;
#pragma unroll
  for (int j = 0; j < 4; j++) {
    float4 v = xr[lane + 64 * j];
    int d0 = (lane + 64 * j) * 4;
    const float* vv = (const float*)&v;
#pragma unroll
    for (int q = 0; q < 4; q++) {
      float xv = vv[q];
      const float4* g = (const float4*)(gw + (size_t)(d0 + q) * NEXP);
      float4 g0 = g[0], g1 = g[1];
      s[0] += (double)xv * g0.x; s[1] += (double)xv * g0.y;
      s[2] += (double)xv * g0.z; s[3] += (double)xv * g0.w;
      s[4] += (double)xv * g1.x; s[5] += (double)xv * g1.y;
      s[6] += (double)xv * g1.z; s[7] += (double)xv * g1.w;
    }
  }
  // full-wave butterfly reduce (wave = 64 lanes)
  for (int m = 1; m < 64; m <<= 1) {
#pragma unroll
    for (int e = 0; e < NEXP; e++) s[e] += __shfl_xor(s[e], m);
  }
  if (lane == 0) {
    double m0 = -1e300; int e0 = 0;
#pragma unroll
    for (int e = 0; e < NEXP; e++) if (s[e] > m0) { m0 = s[e]; e0 = e; }
    double m1 = -1e300; int e1 = (e0 == 0) ? 1 : 0;
#pragma unroll
    for (int e = 0; e < NEXP; e++) if (e != e0 && s[e] > m1) { m1 = s[e]; e1 = e; }
    double ew = exp(m1 - m0);
    float w0 = (float)(1.0 / (1.0 + ew));
    float w1v = (float)(ew / (1.0 + ew));
    route_e[t] = make_int2(e0, e1);
    route_w[t] = make_float2(w0, w1v);
    atomicAdd(&lcnt[e0], 1);
    atomicAdd(&lcnt[e1], 1);
  }
  __syncthreads();
  if (tid < NEXP && lcnt[tid]) atomicAdd(&counts[tid], lcnt[tid]);
}

// ---------------- prefix sum over 8 experts ----------------------------------
__global__ void k_prefix(const int* __restrict__ counts, int* __restrict__ offsets,
                         int* __restrict__ cursors) {
  if (threadIdx.x == 0) {
    int a = 0;
    for (int e = 0; e < NEXP; e++) { offsets[e] = a; cursors[e] = a; a += counts[e]; }
  }
}

// ---------------- assignment: compact pair lists -----------------------------
__global__ __launch_bounds__(256) void k_assign(const int2* __restrict__ route_e,
                                                const float2* __restrict__ route_w,
                                                int* __restrict__ cursors,
                                                int* __restrict__ tok,
                                                float* __restrict__ wtp) {
  __shared__ int lcnt[NEXP];
  __shared__ int lbase[NEXP];
  int tid = threadIdx.x;
  int t = blockIdx.x * 256 + tid;
  if (tid < NEXP) lcnt[tid] = 0;
  __syncthreads();
  int2 e = route_e[t];
  float2 w = route_w[t];
  int r0 = atomicAdd(&lcnt[e.x], 1);
  int r1 = atomicAdd(&lcnt[e.y], 1);
  __syncthreads();
  if (tid < NEXP) lbase[tid] = lcnt[tid] ? atomicAdd(&cursors[tid], lcnt[tid]) : 0;
  __syncthreads();
  int p0 = lbase[e.x] + r0; tok[p0] = t; wtp[p0] = w.x;
  int p1 = lbase[e.y] + r1; tok[p1] = t; wtp[p1] = w.y;
}

// ---------------- fp32 -> fp16 convert (x) -----------------------------------
__global__ __launch_bounds__(256) void k_cvt_x(const float* __restrict__ x,
                                               _Float16* __restrict__ xh) {
  int i = blockIdx.x * 256 + threadIdx.x;
  float4 v = ((const float4*)x)[i];
  half4 o = { (_Float16)v.x, (_Float16)v.y, (_Float16)v.z, (_Float16)v.w };
  ((half4*)xh)[i] = o;
}

// ---------------- transpose+convert: [E][R][C] fp32 -> [E][C][R] fp16 --------
__global__ __launch_bounds__(256) void k_tcvt(const float* __restrict__ in,
                                              _Float16* __restrict__ out,
                                              int R, int C) {
  __shared__ _Float16 tile[64][72];
  int e = blockIdx.z, tc = blockIdx.x, tr = blockIdx.y;
  const float* src = in + ((size_t)e * R + (size_t)tr * 64) * C + (size_t)tc * 64;
  int rr = threadIdx.x >> 4, c4 = (threadIdx.x & 15) * 4;
#pragma unroll
  for (int it = 0; it < 4; it++) {
    int r = rr + it * 16;
    float4 v = *(const float4*)(src + (size_t)r * C + c4);
    tile[r][c4 + 0] = (_Float16)v.x; tile[r][c4 + 1] = (_Float16)v.y;
    tile[r][c4 + 2] = (_Float16)v.z; tile[r][c4 + 3] = (_Float16)v.w;
  }
  __syncthreads();
  _Float16* dst = out + ((size_t)e * C + (size_t)tc * 64) * R + (size_t)tr * 64;
#pragma unroll
  for (int it = 0; it < 4; it++) {
    int c = rr + it * 16;
    half4 o = { tile[c4 + 0][c], tile[c4 + 1][c], tile[c4 + 2][c], tile[c4 + 3][c] };
    *(half4*)(dst + (size_t)c * R + c4) = o;
  }
}

// ---------------- grouped GEMM (m97-style 128x128, BK=64, 4 waves) -----------
// MODE 0: H[pair, chunk_col] = silu( gather(xh)[pair] @ w1T[e] )   (fp16 out)
// MODE 1: out[tok[pair]] += wtp[pair] * ( H[pair] @ w2T[e] )       (atomic f32)
template <int MODE>
__global__ __launch_bounds__(256) void k_gemm(
    const _Float16* __restrict__ A, const _Float16* __restrict__ B,
    const int* __restrict__ counts, const int* __restrict__ offsets,
    const int* __restrict__ tok, const float* __restrict__ wtp,
    _Float16* __restrict__ Hout, float* __restrict__ out,
    int A_stride, int B_row_stride, int B_k_off, int K_len, int n0_global, int CH) {
  int e = blockIdx.x >> 7;
  int tm = blockIdx.x & 127;
  int n_e = counts[e];
  if (tm * 128 >= n_e) return;
  int seg = offsets[e];

  __shared__ _Float16 As[128 * 64];
  __shared__ _Float16 Bs[128 * 64];

  int tid = threadIdx.x, lane = tid & 63, wid = tid >> 6;
  int wr = wid >> 1, wc = wid & 1;
  int colbase = n0_global + blockIdx.y * 128;  // B row index base (global N)

  const _Float16* asrc[4];
  const _Float16* bsrc[4];
  const _Float16* Bexp = B + (size_t)e * ((size_t)DMODEL * HID);
#pragma unroll
  for (int c = 0; c < 4; c++) {
    int rloc = wid * 32 + c * 8 + (lane >> 3);
    int ridx = min(tm * 128 + rloc, n_e - 1);
    size_t arow;
    if (MODE == 0) arow = (size_t)tok[seg + ridx];
    else           arow = (size_t)(seg + ridx);
    asrc[c] = A + arow * (size_t)A_stride + ((lane & 7) * 8);
    int nloc = wid * 32 + c * 8 + (lane >> 3);
    bsrc[c] = Bexp + (size_t)(colbase + nloc) * B_row_stride + B_k_off + ((lane & 7) * 8);
  }

  f32x4 acc[4][4];
#pragma unroll
  for (int m = 0; m < 4; m++)
#pragma unroll
    for (int n = 0; n < 4; n++) acc[m][n] = (f32x4){0.f, 0.f, 0.f, 0.f};

  for (int k0 = 0; k0 < K_len; k0 += 64) {
#pragma unroll
    for (int c = 0; c < 4; c++) {
      gload_lds16(asrc[c] + k0, As + (wid * 4 + c) * 512);
      gload_lds16(bsrc[c] + k0, Bs + (wid * 4 + c) * 512);
    }
    __syncthreads();
#pragma unroll
    for (int kk = 0; kk < 64; kk += 32) {
      half8 af[4], bf[4];
#pragma unroll
      for (int m = 0; m < 4; m++)
        af[m] = *(const half8*)(As + (wr * 64 + m * 16 + (lane & 15)) * 64 + kk + ((lane >> 4) * 8));
#pragma unroll
      for (int n = 0; n < 4; n++)
        bf[n] = *(const half8*)(Bs + (wc * 64 + n * 16 + (lane & 15)) * 64 + kk + ((lane >> 4) * 8));
#pragma unroll
      for (int m = 0; m < 4; m++)
#pragma unroll
        for (int n = 0; n < 4; n++)
          acc[m][n] = __builtin_amdgcn_mfma_f32_16x16x32_f16(af[m], bf[n], acc[m][n], 0, 0, 0);
    }
    __syncthreads();
  }

  int cbase = wc * 64 + (lane & 15);
#pragma unroll
  for (int m = 0; m < 4; m++) {
    int rb = wr * 64 + m * 16 + ((lane >> 4) << 2);
#pragma unroll
    for (int r = 0; r < 4; r++) {
      int grow = tm * 128 + rb + r;
      if (grow >= n_e) continue;
      int gp = seg + grow;
      if (MODE == 0) {
        _Float16* hrow = Hout + (size_t)gp * CH + blockIdx.y * 128 + cbase;
#pragma unroll
        for (int n = 0; n < 4; n++) {
          float v = acc[m][n][r];
          float sv = v / (1.f + __expf(-v));
          hrow[n * 16] = (_Float16)sv;
        }
      } else {
        float wt = wtp[gp];
        int t = tok[gp];
        float* orow = out + (size_t)t * DMODEL + colbase + cbase;
#pragma unroll
        for (int n = 0; n < 4; n++)
          atomicAdd(orow + n * 16, wt * acc[m][n][r]);
      }
    }
  }
}

// -----------------------------------------------------------------------------
extern "C" void kernel_launch(void* const* d_in, const int* in_sizes, int n_in,
                              void* d_out, int out_size, void* d_ws, size_t ws_size,
                              hipStream_t stream) {
  const float* x  = (const float*)d_in[0];
  const float* gw = (const float*)d_in[1];
  const float* w1 = (const float*)d_in[2];
  const float* w2 = (const float*)d_in[3];
  float* out = (float*)d_out;

  char* p = (char*)d_ws;
  int* counts  = (int*)p;
  int* cursors = (int*)(p + 64);
  int* offsets = (int*)(p + 128);
  p += 4096;
  int2*   route_e = (int2*)p;   p += (size_t)T_TOKENS * 8;
  float2* route_w = (float2*)p; p += (size_t)T_TOKENS * 8;
  int*    tok = (int*)p;        p += (size_t)NPAIRS * 4;
  float*  wtp = (float*)p;      p += (size_t)NPAIRS * 4;
  _Float16* xh  = (_Float16*)p; p += (size_t)T_TOKENS * DMODEL * 2;
  _Float16* w1T = (_Float16*)p; p += (size_t)NEXP * DMODEL * HID * 2;
  _Float16* w2T = (_Float16*)p; p += (size_t)NEXP * DMODEL * HID * 2;
  size_t used = (size_t)(p - (char*)d_ws);
  int CH = HID;
  while (CH > 256 && used + (size_t)NPAIRS * CH * 2 > ws_size) CH >>= 1;
  _Float16* Hbuf = (_Float16*)p;

  hipMemsetAsync(counts, 0, 4096, stream);
  hipMemsetAsync(out, 0, (size_t)out_size * 4, stream);

  k_cvt_x<<<T_TOKENS * DMODEL / 4 / 256, 256, 0, stream>>>(x, xh);
  k_tcvt<<<dim3(HID / 64, DMODEL / 64, NEXP), 256, 0, stream>>>(w1, w1T, DMODEL, HID);
  k_tcvt<<<dim3(DMODEL / 64, HID / 64, NEXP), 256, 0, stream>>>(w2, w2T, HID, DMODEL);
  k_gate<<<T_TOKENS / 4, 256, 0, stream>>>(x, gw, route_e, route_w, counts);
  k_prefix<<<1, 64, 0, stream>>>(counts, offsets, cursors);
  k_assign<<<T_TOKENS / 256, 256, 0, stream>>>(route_e, route_w, cursors, tok, wtp);

  for (int h0 = 0; h0 < HID; h0 += CH) {
    // GEMM1: gathered xh @ w1T -> silu -> H (fp16), cols [h0, h0+CH)
    k_gemm<0><<<dim3(NEXP * 128, CH / 128), 256, 0, stream>>>(
        xh, w1T, counts, offsets, tok, wtp, Hbuf, nullptr,
        DMODEL, DMODEL, 0, DMODEL, h0, CH);
    // GEMM2: H @ w2T -> weighted atomic scatter into out
    k_gemm<1><<<dim3(NEXP * 128, DMODEL / 128), 256, 0, stream>>>(
        Hbuf, w2T, counts, offsets, tok, wtp, nullptr, out,
        CH, HID, h0, CH, 0, CH);
  }
}